// Round 4
// baseline (74.843 us; speedup 1.0000x reference)
//
#include <hip/hip_runtime.h>
#include <hip/hip_bf16.h>
#include <math.h>

// Single fused kernel with device-scope completion counter.
//   Phase 1 (168 blocks, 42 rows x 4 k-chunks): fac[r][k] = row_r . W[:,k]
//     (r<32: x row r vs U; else mu row r-32 vs V)
//   Phase 2 (the 32 blocks with ks==0, r<32): spin until all 168 blocks done,
//     then h[r,:] = fac1[r] @ fac2^T and row log-softmax, in wave 0.
// Co-residency: 168 blocks < 256 CUs -> all blocks resident, spin is safe.
// The 256MB ws re-poison fill (~40us @85% HBM) is an unconditional harness
// cost (verified R2); this round removes the kernelA->kernelB dispatch drain.
#define BB 32
#define DD 128
#define KK 512
#define CC 10
#define KSPLIT 4
#define KCH (KK / KSPLIT)          // 128 threads per block
#define NBLK ((BB + CC) * KSPLIT)  // 168

__global__ __launch_bounds__(KCH) void fused_kernel(
    const float* __restrict__ x, const float* __restrict__ mu,
    const float* __restrict__ U, const float* __restrict__ V,
    unsigned int* __restrict__ counter,   // zeroed by memset node each call
    float* __restrict__ fac,              // [42][512] scratch
    float* __restrict__ out)
{
    const int blk = blockIdx.x;           // 0..167
    const int r   = blk / KSPLIT;         // 0..41
    const int ks  = blk - r * KSPLIT;     // 0..3
    const int k   = ks * KCH + threadIdx.x;

    const float* __restrict__ row = (r < BB) ? (x + r * DD) : (mu + (r - BB) * DD);
    const float* __restrict__ W   = (r < BB) ? U : V;

    // --- Phase 1: fac element (dual accumulator chains, deep unroll) ---
    float acc0 = 0.0f, acc1 = 0.0f;
    #pragma unroll 16
    for (int d = 0; d < DD; d += 2) {
        acc0 = fmaf(row[d],     W[d * KK + k],       acc0);
        acc1 = fmaf(row[d + 1], W[(d + 1) * KK + k], acc1);
    }
    fac[r * KK + k] = acc0 + acc1;

    // Release our fac writes to agent scope, then signal completion.
    __threadfence();
    __syncthreads();
    if (threadIdx.x == 0) atomicAdd(counter, 1u);

    // --- Phase 2: 32 designated blocks compute h + log-softmax ---
    if (r < BB && ks == 0) {
        // Spin until all 168 blocks have published fac (acquire: invalidates L1).
        while (__hip_atomic_load(counter, __ATOMIC_ACQUIRE,
                                 __HIP_MEMORY_SCOPE_AGENT) < NBLK) {
            __builtin_amdgcn_s_sleep(1);
        }

        if (threadIdx.x < 64) {
            const int lane = threadIdx.x;
            const float* __restrict__ f1 = fac + r * KK;
            const float* __restrict__ f2 = fac + BB * KK;   // fac2 [10][512]

            const float4* f1v = (const float4*)(f1 + lane * 8);
            const float4 p0 = f1v[0];
            const float4 p1 = f1v[1];

            float hrow[CC];
            #pragma unroll
            for (int c = 0; c < CC; ++c) {
                const float4* f2v = (const float4*)(f2 + c * KK + lane * 8);
                const float4 q0 = f2v[0];
                const float4 q1 = f2v[1];
                float s = p0.x * q0.x + p0.y * q0.y + p0.z * q0.z + p0.w * q0.w
                        + p1.x * q1.x + p1.y * q1.y + p1.z * q1.z + p1.w * q1.w;
                #pragma unroll
                for (int off = 32; off > 0; off >>= 1)
                    s += __shfl_xor(s, off);
                hrow[c] = s;
            }

            float mx = hrow[0];
            #pragma unroll
            for (int c = 1; c < CC; ++c) mx = fmaxf(mx, hrow[c]);
            float sum = 0.0f;
            #pragma unroll
            for (int c = 0; c < CC; ++c) sum += __expf(hrow[c] - mx);
            const float lse = mx + __logf(sum);

            if (lane < CC) {
                float v = hrow[0];
                #pragma unroll
                for (int c = 1; c < CC; ++c) v = (lane == c) ? hrow[c] : v;
                out[r * CC + lane] = v - lse;
            }
        }
    }
}

extern "C" void kernel_launch(void* const* d_in, const int* in_sizes, int n_in,
                              void* d_out, int out_size, void* d_ws, size_t ws_size,
                              hipStream_t stream)
{
    const float* x  = (const float*)d_in[0];   // [32,128]
    const float* mu = (const float*)d_in[1];   // [10,128]
    const float* U  = (const float*)d_in[2];   // [128,512]
    const float* V  = (const float*)d_in[3];   // [128,512]
    float* out = (float*)d_out;                // [32,10]

    unsigned int* counter = (unsigned int*)d_ws;            // 4 bytes
    float* fac = (float*)((char*)d_ws + 512);               // [42][512], aligned

    // Counter must start at 0 every call (ws is re-poisoned to 0xAA).
    hipMemsetAsync(counter, 0, sizeof(unsigned int), stream);
    fused_kernel<<<NBLK, KCH, 0, stream>>>(x, mu, U, V, counter, fac, out);
}

// Round 5
// 63.328 us; speedup vs baseline: 1.1818x; 1.1818x over previous
//
#include <hip/hip_runtime.h>
#include <hip/hip_bf16.h>
#include <math.h>

// Two-kernel split (final architecture — fusion tested twice, both +11us):
//   A: fac[r][k], r in [0,42): r<32 -> x_row r @ U ; else mu_row (r-32) @ V
//   B: h = fac1 @ fac2^T + row log-softmax, 1 wave per batch row.
// Budget (verified R1-R4): ~40us unconditional 256MB ws poison fill @85% HBM
// + ~17us harness restores + ~6us our slice. This round: max load-ILP in A
// (full unroll, 4 chains), front-loaded VMEM in B (loads before shuffles).
#define BB 32
#define DD 128
#define KK 512
#define CC 10
#define KSPLIT 4
#define KCH (KK / KSPLIT)   // 128 threads per block in kernel A

__global__ __launch_bounds__(KCH) void fac_kernel(
    const float* __restrict__ x, const float* __restrict__ mu,
    const float* __restrict__ U, const float* __restrict__ V,
    float* __restrict__ fac)
{
    const int r  = blockIdx.x;            // 0..41
    const int ks = blockIdx.y;            // 0..KSPLIT-1
    const int k  = ks * KCH + threadIdx.x;

    const float* __restrict__ row = (r < BB) ? (x + r * DD) : (mu + (r - BB) * DD);
    const float* __restrict__ W   = (r < BB) ? U : V;

    // Full unroll + 4 independent chains: compiler can keep ~all 128
    // coalesced loads in flight (row[] scalarizes to s_load, free).
    float a0 = 0.0f, a1 = 0.0f, a2 = 0.0f, a3 = 0.0f;
    #pragma unroll
    for (int d = 0; d < DD; d += 4) {
        a0 = fmaf(row[d + 0], W[(d + 0) * KK + k], a0);
        a1 = fmaf(row[d + 1], W[(d + 1) * KK + k], a1);
        a2 = fmaf(row[d + 2], W[(d + 2) * KK + k], a2);
        a3 = fmaf(row[d + 3], W[(d + 3) * KK + k], a3);
    }
    fac[r * KK + k] = (a0 + a1) + (a2 + a3);
}

// One block (1 wave) per batch row. All 22 VMEM loads issued before any
// reduction; butterfly rounds are round-major (10 independent swizzles/round).
__global__ __launch_bounds__(64) void h_softmax_kernel(
    const float* __restrict__ fac, float* __restrict__ out)
{
    const int b    = blockIdx.x;      // 0..31
    const int lane = threadIdx.x;     // 0..63

    const float* __restrict__ f1 = fac + b * KK;
    const float* __restrict__ f2 = fac + BB * KK;   // fac2 base [10][512]

    const float4* f1v = (const float4*)(f1 + lane * 8);
    const float4 p0 = f1v[0];
    const float4 p1 = f1v[1];

    float4 q0[CC], q1[CC];
    #pragma unroll
    for (int c = 0; c < CC; ++c) {
        const float4* f2v = (const float4*)(f2 + c * KK + lane * 8);
        q0[c] = f2v[0];
        q1[c] = f2v[1];
    }

    float s[CC];
    #pragma unroll
    for (int c = 0; c < CC; ++c) {
        s[c] = p0.x * q0[c].x + p0.y * q0[c].y + p0.z * q0[c].z + p0.w * q0[c].w
             + p1.x * q1[c].x + p1.y * q1[c].y + p1.z * q1[c].z + p1.w * q1[c].w;
    }

    // Round-major butterfly: each round has 10 independent swizzle+adds.
    #pragma unroll
    for (int off = 32; off > 0; off >>= 1) {
        #pragma unroll
        for (int c = 0; c < CC; ++c)
            s[c] += __shfl_xor(s[c], off);
    }

    float mx = s[0];
    #pragma unroll
    for (int c = 1; c < CC; ++c) mx = fmaxf(mx, s[c]);
    float sum = 0.0f;
    #pragma unroll
    for (int c = 0; c < CC; ++c) sum += __expf(s[c] - mx);
    const float lse = mx + __logf(sum);

    if (lane < CC) {
        float v = s[0];
        #pragma unroll
        for (int c = 1; c < CC; ++c) v = (lane == c) ? s[c] : v;
        out[b * CC + lane] = v - lse;
    }
}

extern "C" void kernel_launch(void* const* d_in, const int* in_sizes, int n_in,
                              void* d_out, int out_size, void* d_ws, size_t ws_size,
                              hipStream_t stream)
{
    const float* x  = (const float*)d_in[0];   // [32,128]
    const float* mu = (const float*)d_in[1];   // [10,128]
    const float* U  = (const float*)d_in[2];   // [128,512]
    const float* V  = (const float*)d_in[3];   // [128,512]
    float* out = (float*)d_out;                // [32,10]
    float* fac = (float*)d_ws;                 // [42,512] scratch (86 KB)

    dim3 gridA(BB + CC, KSPLIT);               // 42 x 4 = 168 blocks
    fac_kernel<<<gridA, KCH, 0, stream>>>(x, mu, U, V, fac);
    h_softmax_kernel<<<BB, 64, 0, stream>>>(fac, out);
}